// Round 4
// baseline (287.940 us; speedup 1.0000x reference)
//
#include <hip/hip_runtime.h>
#include <math.h>

#define BB 8
#define CH 128
#define HH 64
#define WWID 64
#define HIN 62
#define WIN 62
#define SPIN (HIN*WIN)      // 3844
#define HP 66
#define WP 66
#define GG 4
#define GCH 32
#define NPIX (BB*HH*WWID)   // 32768

// ---------------- T0: transpose conv_w [Cout][Cin] -> w1t[k][cout] ----------
__global__ __launch_bounds__(256) void t0_wtrans(const float* __restrict__ conv_w,
                                                 float* __restrict__ w1t) {
    int idx = blockIdx.x * 256 + threadIdx.x;      // 0..16383
    int cout = idx >> 7, k = idx & 127;
    w1t[k * CH + cout] = conv_w[cout * CH + k];
}

// ---------------- T1: transpose x NCHW [B][128][3844] -> xt [B][3844][128] --
__global__ __launch_bounds__(256) void t1_xtrans(const float* __restrict__ x,
                                                 float* __restrict__ xt) {
    __shared__ float tile[32][33];
    int b = blockIdx.z;
    int c0 = blockIdx.y * 32;
    int s0 = blockIdx.x * 32;
    int tx = threadIdx.x & 31, ty = threadIdx.x >> 5;   // 32 x 8
    const float* xb = x + (size_t)b * CH * SPIN;
    #pragma unroll
    for (int i = 0; i < 32; i += 8) {
        int c = c0 + ty + i, s = s0 + tx;
        tile[ty + i][tx] = (s < SPIN) ? xb[(size_t)c * SPIN + s] : 0.f;
    }
    __syncthreads();
    float* xtb = xt + (size_t)b * SPIN * CH;
    #pragma unroll
    for (int i = 0; i < 32; i += 8) {
        int s = s0 + ty + i, c = c0 + tx;
        if (s < SPIN) xtb[(size_t)s * CH + c] = tile[tx][ty + i];
    }
}

// ============ GEMM tiling: 64 px/block (one row), 256 thr, 8px x 4ch/thread =
// lane = t&31 -> c = lane*4 ; prow = t>>5 -> pixels prow*8..+7

// ---------------- A: fused conv1x1 (pad=1) + in_proj ------------------------
__global__ __launch_bounds__(256) void kA_conv_inproj(const float* __restrict__ xt,
                                                      const float* __restrict__ w1t,
                                                      const float* __restrict__ conv_b,
                                                      const float* __restrict__ Wm,
                                                      const float* __restrict__ in_b,
                                                      float* __restrict__ y,
                                                      float* __restrict__ xpad) {
    __shared__ float xs[64 * CH];                   // 32 KB, x-tile then y-tile
    int pix0 = blockIdx.x * 64;
    int t = threadIdx.x;
    float4* xs4 = (float4*)xs;
    int h = (pix0 >> 6) & 63, b = pix0 >> 12;
    bool hin = (h >= 1 && h <= 62);
    for (int q = t; q < 2048; q += 256) {
        int p = q >> 5, c4 = q & 31;                // p = w
        float4 v = make_float4(0.f, 0.f, 0.f, 0.f);
        if (hin && p >= 1 && p <= 62) {
            const float4* src = (const float4*)(xt + (size_t)((b * HIN + (h - 1)) * WIN + (p - 1)) * CH);
            v = src[c4];
        }
        xs4[q] = v;
    }
    __syncthreads();
    int lane = t & 31, prow = t >> 5;
    int c = lane * 4, p0 = prow * 8;
    float4 acc[8];
    float4 bv = *(const float4*)&conv_b[c];
    #pragma unroll
    for (int i = 0; i < 8; i++) acc[i] = bv;
    #pragma unroll 2
    for (int k = 0; k < CH; k += 4) {
        float4 w0 = *(const float4*)&w1t[(k + 0) * CH + c];
        float4 w1 = *(const float4*)&w1t[(k + 1) * CH + c];
        float4 w2 = *(const float4*)&w1t[(k + 2) * CH + c];
        float4 w3 = *(const float4*)&w1t[(k + 3) * CH + c];
        #pragma unroll
        for (int i = 0; i < 8; i++) {
            float4 xv = *(const float4*)&xs[(p0 + i) * CH + k];
            acc[i].x += xv.x * w0.x + xv.y * w1.x + xv.z * w2.x + xv.w * w3.x;
            acc[i].y += xv.x * w0.y + xv.y * w1.y + xv.z * w2.y + xv.w * w3.y;
            acc[i].z += xv.x * w0.z + xv.y * w1.z + xv.z * w2.z + xv.w * w3.z;
            acc[i].w += xv.x * w0.w + xv.y * w1.w + xv.z * w2.w + xv.w * w3.w;
        }
    }
    __syncthreads();                                // everyone done reading x-tile
    #pragma unroll
    for (int i = 0; i < 8; i++) {
        *(float4*)&y[(size_t)(pix0 + p0 + i) * CH + c] = acc[i];
        *(float4*)&xs[(p0 + i) * CH + c] = acc[i];  // y-tile into LDS
    }
    __syncthreads();
    float4 acc2[8];
    float4 bv2 = *(const float4*)&in_b[c];
    #pragma unroll
    for (int i = 0; i < 8; i++) acc2[i] = bv2;
    #pragma unroll 2
    for (int k = 0; k < CH; k += 4) {
        float4 w0 = *(const float4*)&Wm[(k + 0) * CH + c];
        float4 w1 = *(const float4*)&Wm[(k + 1) * CH + c];
        float4 w2 = *(const float4*)&Wm[(k + 2) * CH + c];
        float4 w3 = *(const float4*)&Wm[(k + 3) * CH + c];
        #pragma unroll
        for (int i = 0; i < 8; i++) {
            float4 xv = *(const float4*)&xs[(p0 + i) * CH + k];
            acc2[i].x += xv.x * w0.x + xv.y * w1.x + xv.z * w2.x + xv.w * w3.x;
            acc2[i].y += xv.x * w0.y + xv.y * w1.y + xv.z * w2.y + xv.w * w3.y;
            acc2[i].z += xv.x * w0.z + xv.y * w1.z + xv.z * w2.z + xv.w * w3.z;
            acc2[i].w += xv.x * w0.w + xv.y * w1.w + xv.z * w2.w + xv.w * w3.w;
        }
    }
    #pragma unroll
    for (int i = 0; i < 8; i++) {
        int w = p0 + i;
        *(float4*)&xpad[(size_t)(((b * HP) + h + 1) * WP + (w + 1)) * CH + c] = acc2[i];
    }
}

// ---------------- B: depthwise 3x3 + LayerNorm + GELU -> d ------------------
__global__ __launch_bounds__(256) void kB_dwln(const float* __restrict__ y,
                                               const float* __restrict__ dw_w,
                                               const float* __restrict__ dw_b,
                                               const float* __restrict__ ln_g,
                                               const float* __restrict__ ln_b,
                                               float* __restrict__ d) {
    int t = threadIdx.x;
    int pl = t >> 7;
    int pix = blockIdx.x * 2 + pl;
    int c = t & 127;
    int w = pix & 63, h = (pix >> 6) & 63, b = pix >> 12;
    float acc = dw_b[c];
    #pragma unroll
    for (int ky = 0; ky < 3; ky++) {
        int hh = h + ky - 1;
        if (hh < 0 || hh > 63) continue;
        #pragma unroll
        for (int kx = 0; kx < 3; kx++) {
            int ww = w + kx - 1;
            if (ww < 0 || ww > 63) continue;
            acc += y[(size_t)((b * HH + hh) * WWID + ww) * CH + c] * dw_w[c * 9 + ky * 3 + kx];
        }
    }
    float s = acc, ss = acc * acc;
    #pragma unroll
    for (int off = 1; off < 64; off <<= 1) {
        s  += __shfl_xor(s, off);
        ss += __shfl_xor(ss, off);
    }
    __shared__ float red[8];
    int wave = t >> 6;
    if ((t & 63) == 0) { red[wave * 2] = s; red[wave * 2 + 1] = ss; }
    __syncthreads();
    float S  = red[pl * 4 + 0] + red[pl * 4 + 2];
    float SS = red[pl * 4 + 1] + red[pl * 4 + 3];
    float mu = S * (1.f / 128.f);
    float var = SS * (1.f / 128.f) - mu * mu;
    float xln = (acc - mu) * rsqrtf(var + 1e-5f) * ln_g[c] + ln_b[c];
    float gel = 0.5f * xln * (1.f + erff(xln * 0.70710678118654752f));
    d[(size_t)pix * CH + c] = gel;
}

// ------ C: offset+mask GEMM, softmax, tap precompute -> tapmeta -------------
// tapmeta record per (pix, g*9+p): int4 corner offsets, float4 corner weights (32 B)
__global__ __launch_bounds__(256) void kC_offmask(const float* __restrict__ din,
                                                  const float* __restrict__ off_w,
                                                  const float* __restrict__ off_b,
                                                  const float* __restrict__ mask_w,
                                                  const float* __restrict__ mask_b,
                                                  float* __restrict__ tapmeta) {
    __shared__ float xs[64 * CH];                  // d-tile, then om (stride 108)
    int pix0 = blockIdx.x * 64;
    int t = threadIdx.x;
    const float4* src = (const float4*)(din + (size_t)pix0 * CH);
    float4* xs4 = (float4*)xs;
    for (int q = t; q < 2048; q += 256) xs4[q] = src[q];
    __syncthreads();
    int lane = t & 31, prow = t >> 5;
    int c = lane * 4, p0 = prow * 8;
    const float* wbase; int wstride, cc;
    float4 bv = make_float4(0.f, 0.f, 0.f, 0.f);
    if (lane < 18)      { wbase = off_w;  wstride = 72; cc = c;      bv = *(const float4*)&off_b[c]; }
    else if (lane < 27) { wbase = mask_w; wstride = 36; cc = c - 72; bv = *(const float4*)&mask_b[c - 72]; }
    else                { wbase = mask_w; wstride = 36; cc = 0; }
    float4 acc[8];
    #pragma unroll
    for (int i = 0; i < 8; i++) acc[i] = bv;
    #pragma unroll 2
    for (int k = 0; k < CH; k += 4) {
        float4 w0 = *(const float4*)&wbase[(k + 0) * wstride + cc];
        float4 w1 = *(const float4*)&wbase[(k + 1) * wstride + cc];
        float4 w2 = *(const float4*)&wbase[(k + 2) * wstride + cc];
        float4 w3 = *(const float4*)&wbase[(k + 3) * wstride + cc];
        #pragma unroll
        for (int i = 0; i < 8; i++) {
            float4 xv = *(const float4*)&xs[(p0 + i) * CH + k];
            acc[i].x += xv.x * w0.x + xv.y * w1.x + xv.z * w2.x + xv.w * w3.x;
            acc[i].y += xv.x * w0.y + xv.y * w1.y + xv.z * w2.y + xv.w * w3.y;
            acc[i].z += xv.x * w0.z + xv.y * w1.z + xv.z * w2.z + xv.w * w3.z;
            acc[i].w += xv.x * w0.w + xv.y * w1.w + xv.z * w2.w + xv.w * w3.w;
        }
    }
    __syncthreads();                               // d-tile reads done
    if (lane < 27) {
        #pragma unroll
        for (int i = 0; i < 8; i++)
            *(float4*)&xs[(p0 + i) * 108 + c] = acc[i];   // om rows, stride 108
    }
    __syncthreads();
    // tap phase: thread -> (px, g); 64*4 = 256 exactly
    int px = t >> 2, g = t & 3;
    int pix = pix0 + px;
    int w = px, h = (pix0 >> 6) & 63;
    const float* row = &xs[px * 108];
    // softmax over 9 logits
    float lg[9];
    #pragma unroll
    for (int i = 0; i < 9; i++) lg[i] = row[72 + g * 9 + i];
    float mx = lg[0];
    #pragma unroll
    for (int i = 1; i < 9; i++) mx = fmaxf(mx, lg[i]);
    float e[9], sum = 0.f;
    #pragma unroll
    for (int i = 0; i < 9; i++) { e[i] = expf(lg[i] - mx); sum += e[i]; }
    float inv = 1.f / sum;
    float* tm = tapmeta + ((size_t)pix * 36 + g * 9) * 8;
    #pragma unroll
    for (int p = 0; p < 9; p++) {
        int gp = g * 9 + p;
        float offx = row[gp * 2];
        float offy = row[gp * 2 + 1];
        float m = e[p] * inv;
        float ix = (float)(w + (p / 3)) + offx;
        float iy = (float)(h + (p % 3)) + offy;
        float x0f = floorf(ix), y0f = floorf(iy);
        float fx = ix - x0f, fy = iy - y0f;
        int x0 = (int)x0f, y0 = (int)y0f;
        int xi[4] = { x0, x0 + 1, x0,     x0 + 1 };
        int yi[4] = { y0, y0,     y0 + 1, y0 + 1 };
        float wt[4] = { m * (1.f - fx) * (1.f - fy), m * fx * (1.f - fy),
                        m * (1.f - fx) * fy,         m * fx * fy };
        int lo[4];
        #pragma unroll
        for (int cnr = 0; cnr < 4; cnr++) {
            bool vv = ((unsigned)xi[cnr] < (unsigned)WP) && ((unsigned)yi[cnr] < (unsigned)HP);
            int xc = min(max(xi[cnr], 0), WP - 1), yc = min(max(yi[cnr], 0), HP - 1);
            lo[cnr] = (yc * WP + xc) * CH;
            if (!vv) wt[cnr] = 0.f;
        }
        *(int4*)&tm[p * 8]       = make_int4(lo[0], lo[1], lo[2], lo[3]);
        *(float4*)&tm[p * 8 + 4] = make_float4(wt[0], wt[1], wt[2], wt[3]);
    }
}

// ---------------- D: pure gather-and-accumulate sampling -> core ------------
__global__ __launch_bounds__(256) void kD_gather(const float* __restrict__ xpad,
                                                 const float* __restrict__ tapmeta,
                                                 float* __restrict__ core) {
    __shared__ float meta[2 * 36 * 8];             // 2.25 KB
    int t = threadIdx.x;
    int pix0 = blockIdx.x * 2;
    const float4* src = (const float4*)(tapmeta + (size_t)pix0 * 36 * 8);
    if (t < 144) ((float4*)meta)[t] = src[t];
    __syncthreads();
    int pl = t >> 7, tt = t & 127, g = tt >> 5, cl = tt & 31;
    int pix = pix0 + pl;
    int b = pix >> 12;
    const float* base = xpad + (size_t)b * HP * WP * CH + g * GCH + cl;
    float acc = 0.f;
    #pragma unroll
    for (int p = 0; p < 9; p++) {
        const float* rec = &meta[(pl * 36 + g * 9 + p) * 8];
        int4   o  = *(const int4*)rec;
        float4 wv = *(const float4*)(rec + 4);
        acc += wv.x * base[o.x] + wv.y * base[o.y] + wv.z * base[o.z] + wv.w * base[o.w];
    }
    core[(size_t)pix * CH + tt] = acc;
}

// ---------------- E: out_proj GEMM + NHWC->NCHW store -----------------------
__global__ __launch_bounds__(256) void kE_outproj(const float* __restrict__ core,
                                                  const float* __restrict__ Wm,
                                                  const float* __restrict__ bias,
                                                  float* __restrict__ out) {
    __shared__ float smem[64 * 129];
    int pix0 = blockIdx.x * 64;
    int t = threadIdx.x;
    const float4* src = (const float4*)(core + (size_t)pix0 * CH);
    float4* xs4 = (float4*)smem;
    for (int q = t; q < 2048; q += 256) xs4[q] = src[q];
    __syncthreads();
    int lane = t & 31, prow = t >> 5;
    int c = lane * 4, p0 = prow * 8;
    float4 acc[8];
    float4 bv = *(const float4*)&bias[c];
    #pragma unroll
    for (int i = 0; i < 8; i++) acc[i] = bv;
    #pragma unroll 2
    for (int k = 0; k < CH; k += 4) {
        float4 w0 = *(const float4*)&Wm[(k + 0) * CH + c];
        float4 w1 = *(const float4*)&Wm[(k + 1) * CH + c];
        float4 w2 = *(const float4*)&Wm[(k + 2) * CH + c];
        float4 w3 = *(const float4*)&Wm[(k + 3) * CH + c];
        #pragma unroll
        for (int i = 0; i < 8; i++) {
            float4 xv = *(const float4*)&smem[(p0 + i) * CH + k];
            acc[i].x += xv.x * w0.x + xv.y * w1.x + xv.z * w2.x + xv.w * w3.x;
            acc[i].y += xv.x * w0.y + xv.y * w1.y + xv.z * w2.y + xv.w * w3.y;
            acc[i].z += xv.x * w0.z + xv.y * w1.z + xv.z * w2.z + xv.w * w3.z;
            acc[i].w += xv.x * w0.w + xv.y * w1.w + xv.z * w2.w + xv.w * w3.w;
        }
    }
    __syncthreads();
    #pragma unroll
    for (int i = 0; i < 8; i++) {
        int row = (p0 + i) * 129 + c;
        smem[row + 0] = acc[i].x;
        smem[row + 1] = acc[i].y;
        smem[row + 2] = acc[i].z;
        smem[row + 3] = acc[i].w;
    }
    __syncthreads();
    int b = pix0 >> 12, h = (pix0 >> 6) & 63;
    for (int q = t; q < 8192; q += 256) {
        int cc = q >> 6, ww = q & 63;
        out[(size_t)((b * CH + cc) * HH + h) * WWID + ww] = smem[ww * 129 + cc];
    }
}

extern "C" void kernel_launch(void* const* d_in, const int* in_sizes, int n_in,
                              void* d_out, int out_size, void* d_ws, size_t ws_size,
                              hipStream_t stream) {
    const float* x        = (const float*)d_in[0];
    const float* conv_w   = (const float*)d_in[1];
    const float* conv_b   = (const float*)d_in[2];
    const float* in_proj_w= (const float*)d_in[3];
    const float* in_proj_b= (const float*)d_in[4];
    const float* dw_w     = (const float*)d_in[5];
    const float* dw_b     = (const float*)d_in[6];
    const float* ln_g     = (const float*)d_in[7];
    const float* ln_b     = (const float*)d_in[8];
    const float* off_w    = (const float*)d_in[9];
    const float* off_b    = (const float*)d_in[10];
    const float* mask_w   = (const float*)d_in[11];
    const float* mask_b   = (const float*)d_in[12];
    const float* out_proj_w = (const float*)d_in[13];
    const float* out_proj_b = (const float*)d_in[14];
    float* out = (float*)d_out;

    float* ws = (float*)d_ws;
    // workspace (floats): xt | w1t | y(=core) | xpad | d | tapmeta  ~ 105 MB total
    const size_t O_XT   = 0;                      // 3,936,512
    const size_t O_W1T  = 3936512;                // 16,384
    const size_t O_Y    = O_W1T + 16384;          // 4,194,304 (core aliases y)
    const size_t O_XPAD = O_Y + 4194304;          // 4,460,544
    const size_t O_D    = O_XPAD + 4460544;       // 4,194,304
    const size_t O_TM   = O_D + 4194304;          // 32768*36*8 = 9,437,184
    float* xt   = ws + O_XT;
    float* w1t  = ws + O_W1T;
    float* y    = ws + O_Y;
    float* core = ws + O_Y;       // alias: y dead after kB
    float* xpad = ws + O_XPAD;
    float* dbuf = ws + O_D;
    float* tapmeta = ws + O_TM;

    t0_wtrans<<<64, 256, 0, stream>>>(conv_w, w1t);
    t1_xtrans<<<dim3(121, 4, 8), 256, 0, stream>>>(x, xt);
    hipMemsetAsync(xpad, 0, (size_t)8 * HP * WP * CH * sizeof(float), stream);
    kA_conv_inproj<<<NPIX / 64, 256, 0, stream>>>(xt, w1t, conv_b, in_proj_w, in_proj_b, y, xpad);
    kB_dwln<<<NPIX / 2, 256, 0, stream>>>(y, dw_w, dw_b, ln_g, ln_b, dbuf);
    kC_offmask<<<NPIX / 64, 256, 0, stream>>>(dbuf, off_w, off_b, mask_w, mask_b, tapmeta);
    kD_gather<<<NPIX / 2, 256, 0, stream>>>(xpad, tapmeta, core);
    kE_outproj<<<NPIX / 64, 256, 0, stream>>>(core, out_proj_w, out_proj_b, out);
}

// Round 5
// 220.025 us; speedup vs baseline: 1.3087x; 1.3087x over previous
//
#include <hip/hip_runtime.h>
#include <math.h>

#define BB 8
#define CH 128
#define HH 64
#define WWID 64
#define HIN 62
#define WIN 62
#define SPIN (HIN*WIN)      // 3844
#define HP 66
#define WP 66
#define GG 4
#define GCH 32
#define NPIX (BB*HH*WWID)   // 32768
#define ASTRIDE 136         // LDS A-tile row stride in halfs (16B-aligned rows)

typedef _Float16 v8h __attribute__((ext_vector_type(8)));
typedef float    v4f __attribute__((ext_vector_type(4)));

// ---- P0: pack all 4 weight matrices into MFMA B-fragment order (f16) -------
// frag layout: fi = nt*256 + kc*64 + lane ; element j: k=kc*32+(lane>>4)*8+j,
// n = nt*16 + (lane&15). Matrices: 0=conv(transposed) 1=in_proj 2=off|mask 3=out_proj
__global__ __launch_bounds__(256) void p0_pack(const float* __restrict__ conv_w,
                                               const float* __restrict__ in_proj_w,
                                               const float* __restrict__ off_w,
                                               const float* __restrict__ mask_w,
                                               const float* __restrict__ out_proj_w,
                                               _Float16* __restrict__ wp) {
    int tid = blockIdx.x * 256 + threadIdx.x;       // 0..7935
    if (tid >= 7936) return;
    int mat, base;
    if (tid < 2048)      { mat = 0; base = 0; }
    else if (tid < 4096) { mat = 1; base = 2048; }
    else if (tid < 5888) { mat = 2; base = 4096; }
    else                 { mat = 3; base = 5888; }
    int fi = tid - base;
    int nt = fi >> 8, rem = fi & 255, kc = rem >> 6, lane = rem & 63;
    int n = nt * 16 + (lane & 15);
    int kbase = kc * 32 + ((lane >> 4) & 3) * 8;
    _Float16* dst = wp + (size_t)tid * 8;
    #pragma unroll
    for (int j = 0; j < 8; j++) {
        int k = kbase + j;
        float v;
        if (mat == 0)      v = conv_w[n * CH + k];            // transpose
        else if (mat == 1) v = in_proj_w[k * CH + n];
        else if (mat == 2) v = (n < 72) ? off_w[k * 72 + n]
                               : (n < 108 ? mask_w[k * 36 + (n - 72)] : 0.f);
        else               v = out_proj_w[k * CH + n];
        dst[j] = (_Float16)v;
    }
}

// ---- MFMA core: A-tile in LDS (64 x 128, stride ASTRIDE), packed B ---------
template<int NT>
__device__ inline void mfma_loop(const _Float16* __restrict__ a16,
                                 const _Float16* __restrict__ wp,
                                 v4f acc[NT], int t) {
    int lane = t & 63;
    int wv = t >> 6;                                // m-tile
    const _Float16* abase = a16 + (wv * 16 + (lane & 15)) * ASTRIDE + ((lane >> 4) * 8);
    #pragma unroll
    for (int kc = 0; kc < 4; kc++) {
        v8h av = *(const v8h*)(abase + kc * 32);
        #pragma unroll
        for (int nt = 0; nt < NT; nt++) {
            v8h bv = *(const v8h*)(wp + ((size_t)(nt * 4 + kc) * 64 + lane) * 8);
            acc[nt] = __builtin_amdgcn_mfma_f32_16x16x32_f16(av, bv, acc[nt], 0, 0, 0);
        }
    }
}

// ---- G1: conv1x1 (pad=1) via MFMA; stages x (NCHW) -> A-tile directly ------
__global__ __launch_bounds__(256) void g1_conv(const float* __restrict__ x,
                                               const _Float16* __restrict__ wp,
                                               const float* __restrict__ conv_b,
                                               float* __restrict__ y) {
    __shared__ _Float16 a16[64 * ASTRIDE];
    int pix0 = blockIdx.x * 64;                     // one output row
    int t = threadIdx.x;
    int h = (pix0 >> 6) & 63, b = pix0 >> 12;
    bool hin = (h >= 1 && h <= 62);
    for (int q = t; q < 8192; q += 256) {
        int c = q >> 6, w = q & 63;
        float v = 0.f;
        if (hin && w >= 1 && w <= 62)
            v = x[((size_t)(b * CH + c)) * SPIN + (h - 1) * WIN + (w - 1)];
        a16[w * ASTRIDE + c] = (_Float16)v;
    }
    __syncthreads();
    int lane = t & 63, ncol = lane & 15;
    v4f acc[8];
    #pragma unroll
    for (int nt = 0; nt < 8; nt++) {
        float bv = conv_b[nt * 16 + ncol];
        acc[nt] = (v4f){bv, bv, bv, bv};
    }
    mfma_loop<8>(a16, wp, acc, t);
    int m0 = (t >> 6) * 16 + ((lane >> 4) * 4);
    #pragma unroll
    for (int nt = 0; nt < 8; nt++)
        #pragma unroll
        for (int r = 0; r < 4; r++)
            y[(size_t)(pix0 + m0 + r) * CH + nt * 16 + ncol] = acc[nt][r];
}

// ---- G2: in_proj via MFMA -> xpad interior ---------------------------------
__global__ __launch_bounds__(256) void g2_inproj(const float* __restrict__ y,
                                                 const _Float16* __restrict__ wp,
                                                 const float* __restrict__ bias,
                                                 float* __restrict__ xpad) {
    __shared__ _Float16 a16[64 * ASTRIDE];
    int pix0 = blockIdx.x * 64;
    int t = threadIdx.x;
    const float4* src = (const float4*)(y + (size_t)pix0 * CH);
    for (int q = t; q < 2048; q += 256) {
        float4 v = src[q];
        int p = q >> 5, c4 = q & 31;
        _Float16* d = &a16[p * ASTRIDE + c4 * 4];
        d[0] = (_Float16)v.x; d[1] = (_Float16)v.y;
        d[2] = (_Float16)v.z; d[3] = (_Float16)v.w;
    }
    __syncthreads();
    int lane = t & 63, ncol = lane & 15;
    v4f acc[8];
    #pragma unroll
    for (int nt = 0; nt < 8; nt++) {
        float bv = bias[nt * 16 + ncol];
        acc[nt] = (v4f){bv, bv, bv, bv};
    }
    mfma_loop<8>(a16, wp, acc, t);
    int m0 = (t >> 6) * 16 + ((lane >> 4) * 4);
    int h = (pix0 >> 6) & 63, b = pix0 >> 12;
    #pragma unroll
    for (int nt = 0; nt < 8; nt++)
        #pragma unroll
        for (int r = 0; r < 4; r++) {
            int w = m0 + r;                          // block = one row
            xpad[(size_t)(((b * HP) + h + 1) * WP + (w + 1)) * CH + nt * 16 + ncol] = acc[nt][r];
        }
}

// ---- kB: depthwise 3x3 + LayerNorm + GELU -> d (fp32, unchanged) -----------
__global__ __launch_bounds__(256) void kB_dwln(const float* __restrict__ y,
                                               const float* __restrict__ dw_w,
                                               const float* __restrict__ dw_b,
                                               const float* __restrict__ ln_g,
                                               const float* __restrict__ ln_b,
                                               float* __restrict__ d) {
    int t = threadIdx.x;
    int pl = t >> 7;
    int pix = blockIdx.x * 2 + pl;
    int c = t & 127;
    int w = pix & 63, h = (pix >> 6) & 63, b = pix >> 12;
    float acc = dw_b[c];
    #pragma unroll
    for (int ky = 0; ky < 3; ky++) {
        int hh = h + ky - 1;
        if (hh < 0 || hh > 63) continue;
        #pragma unroll
        for (int kx = 0; kx < 3; kx++) {
            int ww = w + kx - 1;
            if (ww < 0 || ww > 63) continue;
            acc += y[(size_t)((b * HH + hh) * WWID + ww) * CH + c] * dw_w[c * 9 + ky * 3 + kx];
        }
    }
    float s = acc, ss = acc * acc;
    #pragma unroll
    for (int off = 1; off < 64; off <<= 1) {
        s  += __shfl_xor(s, off);
        ss += __shfl_xor(ss, off);
    }
    __shared__ float red[8];
    int wave = t >> 6;
    if ((t & 63) == 0) { red[wave * 2] = s; red[wave * 2 + 1] = ss; }
    __syncthreads();
    float S  = red[pl * 4 + 0] + red[pl * 4 + 2];
    float SS = red[pl * 4 + 1] + red[pl * 4 + 3];
    float mu = S * (1.f / 128.f);
    float var = SS * (1.f / 128.f) - mu * mu;
    float xln = (acc - mu) * rsqrtf(var + 1e-5f) * ln_g[c] + ln_b[c];
    float gel = 0.5f * xln * (1.f + erff(xln * 0.70710678118654752f));
    d[(size_t)pix * CH + c] = gel;
}

// ---- G3: off/mask GEMM via MFMA + softmax + tap precompute -> tapmeta ------
__global__ __launch_bounds__(256) void g3_offmask(const float* __restrict__ din,
                                                  const _Float16* __restrict__ wp,
                                                  const float* __restrict__ off_b,
                                                  const float* __restrict__ mask_b,
                                                  float* __restrict__ tapmeta) {
    __shared__ _Float16 a16[64 * ASTRIDE];
    __shared__ float om[64 * 112];
    int pix0 = blockIdx.x * 64;
    int t = threadIdx.x;
    const float4* src = (const float4*)(din + (size_t)pix0 * CH);
    for (int q = t; q < 2048; q += 256) {
        float4 v = src[q];
        int p = q >> 5, c4 = q & 31;
        _Float16* d = &a16[p * ASTRIDE + c4 * 4];
        d[0] = (_Float16)v.x; d[1] = (_Float16)v.y;
        d[2] = (_Float16)v.z; d[3] = (_Float16)v.w;
    }
    __syncthreads();
    int lane = t & 63, ncol = lane & 15;
    v4f acc[7];
    #pragma unroll
    for (int nt = 0; nt < 7; nt++) {
        int n = nt * 16 + ncol;
        float bv = (n < 72) ? off_b[n] : (n < 108 ? mask_b[n - 72] : 0.f);
        acc[nt] = (v4f){bv, bv, bv, bv};
    }
    mfma_loop<7>(a16, wp, acc, t);
    int m0 = (t >> 6) * 16 + ((lane >> 4) * 4);
    #pragma unroll
    for (int nt = 0; nt < 7; nt++)
        #pragma unroll
        for (int r = 0; r < 4; r++)
            om[(m0 + r) * 112 + nt * 16 + ncol] = acc[nt][r];
    __syncthreads();
    // tap phase: thread -> (px, g); 64*4 = 256
    int px = t >> 2, g = t & 3;
    int pix = pix0 + px;
    int w = px, h = (pix0 >> 6) & 63;
    const float* row = &om[px * 112];
    float lg[9];
    #pragma unroll
    for (int i = 0; i < 9; i++) lg[i] = row[72 + g * 9 + i];
    float mx = lg[0];
    #pragma unroll
    for (int i = 1; i < 9; i++) mx = fmaxf(mx, lg[i]);
    float e[9], sum = 0.f;
    #pragma unroll
    for (int i = 0; i < 9; i++) { e[i] = expf(lg[i] - mx); sum += e[i]; }
    float inv = 1.f / sum;
    float* tm = tapmeta + ((size_t)pix * 36 + g * 9) * 8;
    #pragma unroll
    for (int p = 0; p < 9; p++) {
        int gp = g * 9 + p;
        float offx = row[gp * 2];
        float offy = row[gp * 2 + 1];
        float m = e[p] * inv;
        float ix = (float)(w + (p / 3)) + offx;
        float iy = (float)(h + (p % 3)) + offy;
        float x0f = floorf(ix), y0f = floorf(iy);
        float fx = ix - x0f, fy = iy - y0f;
        int x0 = (int)x0f, y0 = (int)y0f;
        int xi[4] = { x0, x0 + 1, x0,     x0 + 1 };
        int yi[4] = { y0, y0,     y0 + 1, y0 + 1 };
        float wt[4] = { m * (1.f - fx) * (1.f - fy), m * fx * (1.f - fy),
                        m * (1.f - fx) * fy,         m * fx * fy };
        int lo[4];
        #pragma unroll
        for (int cnr = 0; cnr < 4; cnr++) {
            bool vv = ((unsigned)xi[cnr] < (unsigned)WP) && ((unsigned)yi[cnr] < (unsigned)HP);
            int xc = min(max(xi[cnr], 0), WP - 1), yc = min(max(yi[cnr], 0), HP - 1);
            lo[cnr] = (yc * WP + xc) * CH;
            if (!vv) wt[cnr] = 0.f;
        }
        *(int4*)&tm[p * 8]       = make_int4(lo[0], lo[1], lo[2], lo[3]);
        *(float4*)&tm[p * 8 + 4] = make_float4(wt[0], wt[1], wt[2], wt[3]);
    }
}

// ---- kD: pure gather-and-accumulate sampling -> core (unchanged) -----------
__global__ __launch_bounds__(256) void kD_gather(const float* __restrict__ xpad,
                                                 const float* __restrict__ tapmeta,
                                                 float* __restrict__ core) {
    __shared__ float meta[2 * 36 * 8];
    int t = threadIdx.x;
    int pix0 = blockIdx.x * 2;
    const float4* src = (const float4*)(tapmeta + (size_t)pix0 * 36 * 8);
    if (t < 144) ((float4*)meta)[t] = src[t];
    __syncthreads();
    int pl = t >> 7, tt = t & 127, g = tt >> 5, cl = tt & 31;
    int pix = pix0 + pl;
    int b = pix >> 12;
    const float* base = xpad + (size_t)b * HP * WP * CH + g * GCH + cl;
    float acc = 0.f;
    #pragma unroll
    for (int p = 0; p < 9; p++) {
        const float* rec = &meta[(pl * 36 + g * 9 + p) * 8];
        int4   o  = *(const int4*)rec;
        float4 wv = *(const float4*)(rec + 4);
        acc += wv.x * base[o.x] + wv.y * base[o.y] + wv.z * base[o.z] + wv.w * base[o.w];
    }
    core[(size_t)pix * CH + tt] = acc;
}

// ---- G4: out_proj via MFMA + NHWC->NCHW store ------------------------------
__global__ __launch_bounds__(256) void g4_outproj(const float* __restrict__ core,
                                                  const _Float16* __restrict__ wp,
                                                  const float* __restrict__ bias,
                                                  float* __restrict__ out) {
    __shared__ _Float16 a16[64 * ASTRIDE];
    __shared__ float res[64 * 129];
    int pix0 = blockIdx.x * 64;
    int t = threadIdx.x;
    const float4* src = (const float4*)(core + (size_t)pix0 * CH);
    for (int q = t; q < 2048; q += 256) {
        float4 v = src[q];
        int p = q >> 5, c4 = q & 31;
        _Float16* d = &a16[p * ASTRIDE + c4 * 4];
        d[0] = (_Float16)v.x; d[1] = (_Float16)v.y;
        d[2] = (_Float16)v.z; d[3] = (_Float16)v.w;
    }
    __syncthreads();
    int lane = t & 63, ncol = lane & 15;
    v4f acc[8];
    #pragma unroll
    for (int nt = 0; nt < 8; nt++) {
        float bv = bias[nt * 16 + ncol];
        acc[nt] = (v4f){bv, bv, bv, bv};
    }
    mfma_loop<8>(a16, wp, acc, t);
    int m0 = (t >> 6) * 16 + ((lane >> 4) * 4);
    #pragma unroll
    for (int nt = 0; nt < 8; nt++)
        #pragma unroll
        for (int r = 0; r < 4; r++)
            res[(m0 + r) * 129 + nt * 16 + ncol] = acc[nt][r];
    __syncthreads();
    int b = pix0 >> 12, h = (pix0 >> 6) & 63;
    for (int q = t; q < 8192; q += 256) {
        int cc = q >> 6, ww = q & 63;
        out[(size_t)((b * CH + cc) * HH + h) * WWID + ww] = res[ww * 129 + cc];
    }
}

extern "C" void kernel_launch(void* const* d_in, const int* in_sizes, int n_in,
                              void* d_out, int out_size, void* d_ws, size_t ws_size,
                              hipStream_t stream) {
    const float* x        = (const float*)d_in[0];
    const float* conv_w   = (const float*)d_in[1];
    const float* conv_b   = (const float*)d_in[2];
    const float* in_proj_w= (const float*)d_in[3];
    const float* in_proj_b= (const float*)d_in[4];
    const float* dw_w     = (const float*)d_in[5];
    const float* dw_b     = (const float*)d_in[6];
    const float* ln_g     = (const float*)d_in[7];
    const float* ln_b     = (const float*)d_in[8];
    const float* off_w    = (const float*)d_in[9];
    const float* off_b    = (const float*)d_in[10];
    const float* mask_w   = (const float*)d_in[11];
    const float* mask_b   = (const float*)d_in[12];
    const float* out_proj_w = (const float*)d_in[13];
    const float* out_proj_b = (const float*)d_in[14];
    float* out = (float*)d_out;

    float* ws = (float*)d_ws;
    // workspace (floats): wp(32768) | y(=core) | xpad | d | tapmeta  ~ 85 MB
    const size_t O_WP   = 0;                      // 63488 halfs = 124 KB (reserve 32768 floats)
    const size_t O_Y    = 32768;                  // 4,194,304
    const size_t O_XPAD = O_Y + 4194304;          // 4,460,544
    const size_t O_D    = O_XPAD + 4460544;       // 4,194,304
    const size_t O_TM   = O_D + 4194304;          // 9,437,184
    _Float16* wp  = (_Float16*)(ws + O_WP);
    float* y      = ws + O_Y;
    float* core   = ws + O_Y;     // alias: y dead after kB/G2
    float* xpad   = ws + O_XPAD;
    float* dbuf   = ws + O_D;
    float* tapmeta= ws + O_TM;

    // packed matrix bases (frag idx * 8 halfs)
    _Float16* wp_conv = wp;                 // frags [0,2048)
    _Float16* wp_in   = wp + (size_t)2048 * 8;
    _Float16* wp_om   = wp + (size_t)4096 * 8;
    _Float16* wp_out  = wp + (size_t)5888 * 8;

    p0_pack<<<31, 256, 0, stream>>>(conv_w, in_proj_w, off_w, mask_w, out_proj_w, wp);
    hipMemsetAsync(xpad, 0, (size_t)8 * HP * WP * CH * sizeof(float), stream);
    g1_conv<<<NPIX / 64, 256, 0, stream>>>(x, wp_conv, conv_b, y);
    g2_inproj<<<NPIX / 64, 256, 0, stream>>>(y, wp_in, in_proj_b, xpad);
    kB_dwln<<<NPIX / 2, 256, 0, stream>>>(y, dw_w, dw_b, ln_g, ln_b, dbuf);
    g3_offmask<<<NPIX / 64, 256, 0, stream>>>(dbuf, wp_om, off_b, mask_b, tapmeta);
    kD_gather<<<NPIX / 2, 256, 0, stream>>>(xpad, tapmeta, core);
    g4_outproj<<<NPIX / 64, 256, 0, stream>>>(core, out_proj_w ? wp_out : wp_out, out_proj_b, out);
}

// Round 6
// 189.984 us; speedup vs baseline: 1.5156x; 1.1581x over previous
//
#include <hip/hip_runtime.h>
#include <math.h>

#define BB 8
#define CH 128
#define HH 64
#define WWID 64
#define HIN 62
#define WIN 62
#define SPIN (HIN*WIN)      // 3844
#define HP 66
#define WP 66
#define GG 4
#define GCH 32
#define NPIX (BB*HH*WWID)   // 32768
#define ASTRIDE 136         // LDS A-tile row stride in halfs

typedef _Float16 v8h __attribute__((ext_vector_type(8)));
typedef _Float16 v4h __attribute__((ext_vector_type(4)));
typedef float    v4f __attribute__((ext_vector_type(4)));

// ---- P0: pack 4 weight mats into MFMA B-frag order (f16) + dwT transpose ---
__global__ __launch_bounds__(256) void p0_pack(const float* __restrict__ conv_w,
                                               const float* __restrict__ in_proj_w,
                                               const float* __restrict__ off_w,
                                               const float* __restrict__ mask_w,
                                               const float* __restrict__ out_proj_w,
                                               const float* __restrict__ dw_w,
                                               _Float16* __restrict__ wp,
                                               float* __restrict__ dwT) {
    int t = threadIdx.x;
    if (blockIdx.x == 31) {                         // dwT[tap][c] transpose
        if (t < 128) {
            #pragma unroll
            for (int tap = 0; tap < 9; tap++) dwT[tap * 128 + t] = dw_w[t * 9 + tap];
        }
        return;
    }
    int tid = blockIdx.x * 256 + t;                 // 0..7935
    int mat, base;
    if (tid < 2048)      { mat = 0; base = 0; }
    else if (tid < 4096) { mat = 1; base = 2048; }
    else if (tid < 5888) { mat = 2; base = 4096; }
    else                 { mat = 3; base = 5888; }
    int fi = tid - base;
    int nt = fi >> 8, rem = fi & 255, kc = rem >> 6, lane = rem & 63;
    int n = nt * 16 + (lane & 15);
    int kbase = kc * 32 + ((lane >> 4) & 3) * 8;
    _Float16* dst = wp + (size_t)tid * 8;
    #pragma unroll
    for (int j = 0; j < 8; j++) {
        int k = kbase + j;
        float v;
        if (mat == 0)      v = conv_w[n * CH + k];
        else if (mat == 1) v = in_proj_w[k * CH + n];
        else if (mat == 2) v = (n < 72) ? off_w[k * 72 + n]
                               : (n < 108 ? mask_w[k * 36 + (n - 72)] : 0.f);
        else               v = out_proj_w[k * CH + n];
        dst[j] = (_Float16)v;
    }
}

// ---- MFMA core: A-tile in LDS (64x128, stride ASTRIDE), packed B -----------
template<int NT>
__device__ inline void mfma_loop(const _Float16* __restrict__ a16,
                                 const _Float16* __restrict__ wp,
                                 v4f acc[NT], int t) {
    int lane = t & 63;
    int wv = t >> 6;
    const _Float16* abase = a16 + (wv * 16 + (lane & 15)) * ASTRIDE + ((lane >> 4) * 8);
    #pragma unroll
    for (int kc = 0; kc < 4; kc++) {
        v8h av = *(const v8h*)(abase + kc * 32);
        #pragma unroll
        for (int nt = 0; nt < NT; nt++) {
            v8h bv = *(const v8h*)(wp + ((size_t)(nt * 4 + kc) * 64 + lane) * 8);
            acc[nt] = __builtin_amdgcn_mfma_f32_16x16x32_f16(av, bv, acc[nt], 0, 0, 0);
        }
    }
}

// write fp32 C-layout accs into a16 as f16 [px][c] (scalar stores)
template<int NT>
__device__ inline void acc_to_a16(_Float16* a16, v4f acc[NT], int t) {
    int lane = t & 63, ncol = lane & 15;
    int m0 = (t >> 6) * 16 + ((lane >> 4) * 4);
    #pragma unroll
    for (int nt = 0; nt < NT; nt++)
        #pragma unroll
        for (int r = 0; r < 4; r++)
            a16[(m0 + r) * ASTRIDE + nt * 16 + ncol] = (_Float16)acc[nt][r];
}

// ---- gA: fused conv1x1(pad=1) + in_proj, all-MFMA; emits y16 + xpad16 ------
__global__ __launch_bounds__(256) void gA_conv_inproj(const float* __restrict__ x,
                                                      const _Float16* __restrict__ wp_conv,
                                                      const _Float16* __restrict__ wp_in,
                                                      const float* __restrict__ conv_b,
                                                      const float* __restrict__ in_b,
                                                      _Float16* __restrict__ y16,
                                                      _Float16* __restrict__ xpad16) {
    __shared__ _Float16 a16[64 * ASTRIDE];
    int pix0 = blockIdx.x * 64;                     // one row
    int t = threadIdx.x;
    int h = (pix0 >> 6) & 63, b = pix0 >> 12;
    bool hin = (h >= 1 && h <= 62);
    for (int q = t; q < 8192; q += 256) {
        int c = q >> 6, w = q & 63;
        float v = 0.f;
        if (hin && w >= 1 && w <= 62)
            v = x[((size_t)(b * CH + c)) * SPIN + (h - 1) * WIN + (w - 1)];
        a16[w * ASTRIDE + c] = (_Float16)v;
    }
    __syncthreads();
    int lane = t & 63, ncol = lane & 15;
    v4f acc[8];
    #pragma unroll
    for (int nt = 0; nt < 8; nt++) {
        float bv = conv_b[nt * 16 + ncol];
        acc[nt] = (v4f){bv, bv, bv, bv};
    }
    mfma_loop<8>(a16, wp_conv, acc, t);
    __syncthreads();                                // x-tile reads done
    acc_to_a16<8>(a16, acc, t);                     // a16 = y tile (f16)
    __syncthreads();
    // copy y tile to global + second GEMM
    {
        _Float16* dst = y16 + (size_t)pix0 * CH;
        for (int q = t; q < 1024; q += 256)
            *(v8h*)&dst[q * 8] = *(const v8h*)&a16[(q >> 4) * ASTRIDE + (q & 15) * 8];
    }
    v4f acc2[8];
    #pragma unroll
    for (int nt = 0; nt < 8; nt++) {
        float bv = in_b[nt * 16 + ncol];
        acc2[nt] = (v4f){bv, bv, bv, bv};
    }
    mfma_loop<8>(a16, wp_in, acc2, t);
    __syncthreads();                                // y-tile reads done
    acc_to_a16<8>(a16, acc2, t);                    // a16 = x_proj tile (f16)
    __syncthreads();
    {
        _Float16* dst = xpad16 + (size_t)(((b * HP) + h + 1) * WP + 1) * CH;
        for (int q = t; q < 1024; q += 256)
            *(v8h*)&dst[q * 8] = *(const v8h*)&a16[(q >> 4) * ASTRIDE + (q & 15) * 8];
    }
}

// ---- gF: fused dw3x3 + LN + GELU + off/mask MFMA + softmax + taps ----------
// phase1 LDS: ylds = 3 rows x 16 c8 x 65(w-stride) v8h  = 49,920 B
// phase2 LDS: a16 (17,408 B) + om 64x112 f32 (28,672 B) = 46,080 B
__global__ __launch_bounds__(256) void gF_dwln_offmask(const _Float16* __restrict__ y16,
                                                       const _Float16* __restrict__ wp_om,
                                                       const float* __restrict__ dwT,
                                                       const float* __restrict__ dw_b,
                                                       const float* __restrict__ ln_g,
                                                       const float* __restrict__ ln_b,
                                                       const float* __restrict__ off_b,
                                                       const float* __restrict__ mask_b,
                                                       float* __restrict__ tapmeta) {
    __shared__ char smem[49920];
    _Float16* ylds = (_Float16*)smem;               // v8h idx: (r*16+c8)*65 + w
    int t = threadIdx.x;
    int pix0 = blockIdx.x * 64;
    int h = (pix0 >> 6) & 63, b = pix0 >> 12;
    if (h == 0 || h == 63) {                        // zero-fill for missing rows
        for (int i = t; i < 3120; i += 256) *(v8h*)&ylds[i * 8] = (v8h)(_Float16)0;
        __syncthreads();
    }
    for (int idx = t; idx < 3072; idx += 256) {
        int r = idx >> 10, w = (idx >> 4) & 63, c8 = idx & 15;
        int hh = h + r - 1;
        if (hh >= 0 && hh <= 63) {
            v8h v = *(const v8h*)&y16[(size_t)(((b * 64 + hh) * 64 + w) * CH) + c8 * 8];
            *(v8h*)&ylds[(size_t)((r * 16 + c8) * 65 + w) * 8] = v;
        }
    }
    __syncthreads();
    // ---- depthwise conv, 1 px x 32 ch per thread ----
    int px = t >> 2, q = t & 3;
    float acc[32];
    #pragma unroll
    for (int cb = 0; cb < 8; cb++) *(float4*)&acc[cb * 4] = *(const float4*)&dw_b[q * 32 + cb * 4];
    #pragma unroll
    for (int r = 0; r < 3; r++) {
        #pragma unroll
        for (int kx = 0; kx < 3; kx++) {
            int wp = px + kx - 1;
            bool valid = (wp >= 0 && wp <= 63);
            int wpc = min(max(wp, 0), 63);
            int tap = r * 3 + kx;
            #pragma unroll
            for (int cb = 0; cb < 4; cb++) {
                v8h yv = *(const v8h*)&ylds[(size_t)((r * 16 + q * 4 + cb) * 65 + wpc) * 8];
                float4 wa = *(const float4*)&dwT[tap * 128 + q * 32 + cb * 8];
                float4 wb = *(const float4*)&dwT[tap * 128 + q * 32 + cb * 8 + 4];
                if (valid) {
                    acc[cb*8+0] += (float)yv[0] * wa.x; acc[cb*8+1] += (float)yv[1] * wa.y;
                    acc[cb*8+2] += (float)yv[2] * wa.z; acc[cb*8+3] += (float)yv[3] * wa.w;
                    acc[cb*8+4] += (float)yv[4] * wb.x; acc[cb*8+5] += (float)yv[5] * wb.y;
                    acc[cb*8+6] += (float)yv[6] * wb.z; acc[cb*8+7] += (float)yv[7] * wb.w;
                }
            }
        }
    }
    // ---- LayerNorm over 128 ch = 4 threads x 32 ----
    float s = 0.f, ss = 0.f;
    #pragma unroll
    for (int j = 0; j < 32; j++) { s += acc[j]; ss += acc[j] * acc[j]; }
    s  += __shfl_xor(s, 1);  s  += __shfl_xor(s, 2);
    ss += __shfl_xor(ss, 1); ss += __shfl_xor(ss, 2);
    float mu = s * (1.f / 128.f);
    float var = ss * (1.f / 128.f) - mu * mu;
    float rstd = rsqrtf(var + 1e-5f);
    v8h dreg[4];
    #pragma unroll
    for (int cb = 0; cb < 4; cb++) {
        float4 ga = *(const float4*)&ln_g[q * 32 + cb * 8];
        float4 gb = *(const float4*)&ln_g[q * 32 + cb * 8 + 4];
        float4 ba = *(const float4*)&ln_b[q * 32 + cb * 8];
        float4 bb = *(const float4*)&ln_b[q * 32 + cb * 8 + 4];
        float gv[8] = {ga.x, ga.y, ga.z, ga.w, gb.x, gb.y, gb.z, gb.w};
        float bv[8] = {ba.x, ba.y, ba.z, ba.w, bb.x, bb.y, bb.z, bb.w};
        #pragma unroll
        for (int j = 0; j < 8; j++) {
            float xln = (acc[cb * 8 + j] - mu) * rstd * gv[j] + bv[j];
            float gel = 0.5f * xln * (1.f + erff(xln * 0.70710678118654752f));
            dreg[cb][j] = (_Float16)gel;
        }
    }
    __syncthreads();                                // ylds dead
    _Float16* a16 = (_Float16*)smem;
    float* om = (float*)(smem + 17408);
    #pragma unroll
    for (int cb = 0; cb < 4; cb++)
        *(v8h*)&a16[px * ASTRIDE + q * 32 + cb * 8] = dreg[cb];
    __syncthreads();
    // ---- off/mask GEMM via MFMA ----
    int lane = t & 63, ncol = lane & 15;
    v4f macc[7];
    #pragma unroll
    for (int nt = 0; nt < 7; nt++) {
        int n = nt * 16 + ncol;
        float bv = (n < 72) ? off_b[n] : (n < 108 ? mask_b[n - 72] : 0.f);
        macc[nt] = (v4f){bv, bv, bv, bv};
    }
    mfma_loop<7>(a16, wp_om, macc, t);
    int m0 = (t >> 6) * 16 + ((lane >> 4) * 4);
    #pragma unroll
    for (int nt = 0; nt < 7; nt++)
        #pragma unroll
        for (int r = 0; r < 4; r++)
            om[(m0 + r) * 112 + nt * 16 + ncol] = macc[nt][r];
    __syncthreads();
    // ---- softmax + tap precompute: thread -> (px, g) ----
    int gx = t & 3;
    const float* row = &om[px * 112];
    float lg[9];
    #pragma unroll
    for (int i = 0; i < 9; i++) lg[i] = row[72 + gx * 9 + i];
    float mx = lg[0];
    #pragma unroll
    for (int i = 1; i < 9; i++) mx = fmaxf(mx, lg[i]);
    float e[9], sum = 0.f;
    #pragma unroll
    for (int i = 0; i < 9; i++) { e[i] = expf(lg[i] - mx); sum += e[i]; }
    float inv = 1.f / sum;
    float* tm = tapmeta + ((size_t)(pix0 + px) * 36 + gx * 9) * 8;
    #pragma unroll
    for (int p = 0; p < 9; p++) {
        int gp = gx * 9 + p;
        float offx = row[gp * 2];
        float offy = row[gp * 2 + 1];
        float m = e[p] * inv;
        float ix = (float)(px + (p / 3)) + offx;
        float iy = (float)(h + (p % 3)) + offy;
        float x0f = floorf(ix), y0f = floorf(iy);
        float fx = ix - x0f, fy = iy - y0f;
        int x0 = (int)x0f, y0 = (int)y0f;
        int xi[4] = { x0, x0 + 1, x0,     x0 + 1 };
        int yi[4] = { y0, y0,     y0 + 1, y0 + 1 };
        float wt[4] = { m * (1.f - fx) * (1.f - fy), m * fx * (1.f - fy),
                        m * (1.f - fx) * fy,         m * fx * fy };
        int lo[4];
        #pragma unroll
        for (int cnr = 0; cnr < 4; cnr++) {
            bool vv = ((unsigned)xi[cnr] < (unsigned)WP) && ((unsigned)yi[cnr] < (unsigned)HP);
            int xc = min(max(xi[cnr], 0), WP - 1), yc = min(max(yi[cnr], 0), HP - 1);
            lo[cnr] = (yc * WP + xc) * CH;
            if (!vv) wt[cnr] = 0.f;
        }
        *(int4*)&tm[p * 8]       = make_int4(lo[0], lo[1], lo[2], lo[3]);
        *(float4*)&tm[p * 8 + 4] = make_float4(wt[0], wt[1], wt[2], wt[3]);
    }
}

// ---- kD: gather sampling, 8 px/block, 4 ch/thread -> core16 ----------------
__global__ __launch_bounds__(256) void kD_gather(const _Float16* __restrict__ xpad16,
                                                 const float* __restrict__ tapmeta,
                                                 _Float16* __restrict__ core16) {
    __shared__ float meta[8 * 36 * 8];              // 9216 B
    int t = threadIdx.x;
    int pix0 = blockIdx.x * 8;
    const float4* src = (const float4*)(tapmeta + (size_t)pix0 * 36 * 8);
    for (int i = t; i < 576; i += 256) ((float4*)meta)[i] = src[i];
    __syncthreads();
    int px_l = t >> 5, lane5 = t & 31;
    int c4 = lane5 * 4, g = lane5 >> 3;
    int pix = pix0 + px_l;
    int b = pix >> 12;
    const _Float16* base = xpad16 + (size_t)b * HP * WP * CH + c4;
    float a0 = 0.f, a1 = 0.f, a2 = 0.f, a3 = 0.f;
    #pragma unroll
    for (int p = 0; p < 9; p++) {
        const float* rec = &meta[(size_t)(px_l * 36 + g * 9 + p) * 8];
        int4   o  = *(const int4*)rec;
        float4 wv = *(const float4*)(rec + 4);
        v4h h0 = *(const v4h*)&base[o.x];
        v4h h1 = *(const v4h*)&base[o.y];
        v4h h2 = *(const v4h*)&base[o.z];
        v4h h3 = *(const v4h*)&base[o.w];
        a0 += wv.x*(float)h0[0] + wv.y*(float)h1[0] + wv.z*(float)h2[0] + wv.w*(float)h3[0];
        a1 += wv.x*(float)h0[1] + wv.y*(float)h1[1] + wv.z*(float)h2[1] + wv.w*(float)h3[1];
        a2 += wv.x*(float)h0[2] + wv.y*(float)h1[2] + wv.z*(float)h2[2] + wv.w*(float)h3[2];
        a3 += wv.x*(float)h0[3] + wv.y*(float)h1[3] + wv.z*(float)h2[3] + wv.w*(float)h3[3];
    }
    v4h res = { (_Float16)a0, (_Float16)a1, (_Float16)a2, (_Float16)a3 };
    *(v4h*)&core16[(size_t)pix * CH + c4] = res;
}

// ---- g4: out_proj via MFMA + NHWC->NCHW store ------------------------------
__global__ __launch_bounds__(256) void g4_outproj(const _Float16* __restrict__ core16,
                                                  const _Float16* __restrict__ wp,
                                                  const float* __restrict__ bias,
                                                  float* __restrict__ out) {
    __shared__ _Float16 a16[64 * ASTRIDE];
    __shared__ float res[64 * 129];
    int pix0 = blockIdx.x * 64;
    int t = threadIdx.x;
    const _Float16* src = core16 + (size_t)pix0 * CH;
    for (int q = t; q < 1024; q += 256)
        *(v8h*)&a16[(q >> 4) * ASTRIDE + (q & 15) * 8] = *(const v8h*)&src[q * 8];
    __syncthreads();
    int lane = t & 63, ncol = lane & 15;
    v4f acc[8];
    #pragma unroll
    for (int nt = 0; nt < 8; nt++) {
        float bv = bias[nt * 16 + ncol];
        acc[nt] = (v4f){bv, bv, bv, bv};
    }
    mfma_loop<8>(a16, wp, acc, t);
    int m0 = (t >> 6) * 16 + ((lane >> 4) * 4);
    #pragma unroll
    for (int nt = 0; nt < 8; nt++)
        #pragma unroll
        for (int r = 0; r < 4; r++)
            res[(m0 + r) * 129 + nt * 16 + ncol] = acc[nt][r];
    __syncthreads();
    int b = pix0 >> 12, h = (pix0 >> 6) & 63;
    for (int q = t; q < 8192; q += 256) {
        int cc = q >> 6, ww = q & 63;
        out[(size_t)((b * CH + cc) * HH + h) * WWID + ww] = res[ww * 129 + cc];
    }
}

extern "C" void kernel_launch(void* const* d_in, const int* in_sizes, int n_in,
                              void* d_out, int out_size, void* d_ws, size_t ws_size,
                              hipStream_t stream) {
    const float* x        = (const float*)d_in[0];
    const float* conv_w   = (const float*)d_in[1];
    const float* conv_b   = (const float*)d_in[2];
    const float* in_proj_w= (const float*)d_in[3];
    const float* in_proj_b= (const float*)d_in[4];
    const float* dw_w     = (const float*)d_in[5];
    const float* dw_b     = (const float*)d_in[6];
    const float* ln_g     = (const float*)d_in[7];
    const float* ln_b     = (const float*)d_in[8];
    const float* off_w    = (const float*)d_in[9];
    const float* off_b    = (const float*)d_in[10];
    const float* mask_w   = (const float*)d_in[11];
    const float* mask_b   = (const float*)d_in[12];
    const float* out_proj_w = (const float*)d_in[13];
    const float* out_proj_b = (const float*)d_in[14];
    float* out = (float*)d_out;

    float* ws = (float*)d_ws;
    // float-offsets: wp(32768) | dwT(2048) | y16 | xpad16 | core16 | tapmeta
    const size_t O_WP   = 0;                       // 7936*8 halfs = 124 KB
    const size_t O_DWT  = 32768;                   // 1152 floats
    const size_t O_Y16  = 34816;                   // 32768*128 halfs = 2,097,152 floats
    const size_t O_XP16 = O_Y16 + 2097152;         // 8*66*66*128 halfs = 2,230,272 floats
    const size_t O_C16  = O_XP16 + 2230272;        // 2,097,152 floats
    const size_t O_TM   = O_C16 + 2097152;         // 9,437,184 floats
    _Float16* wp     = (_Float16*)(ws + O_WP);
    float*    dwT    = ws + O_DWT;
    _Float16* y16    = (_Float16*)(ws + O_Y16);
    _Float16* xpad16 = (_Float16*)(ws + O_XP16);
    _Float16* core16 = (_Float16*)(ws + O_C16);
    float*    tapmeta= ws + O_TM;

    _Float16* wp_conv = wp;
    _Float16* wp_in   = wp + (size_t)2048 * 8;
    _Float16* wp_om   = wp + (size_t)4096 * 8;
    _Float16* wp_out  = wp + (size_t)5888 * 8;

    p0_pack<<<32, 256, 0, stream>>>(conv_w, in_proj_w, off_w, mask_w, out_proj_w, dw_w, wp, dwT);
    hipMemsetAsync(xpad16, 0, (size_t)8 * HP * WP * CH * sizeof(_Float16), stream);
    gA_conv_inproj<<<NPIX / 64, 256, 0, stream>>>(x, wp_conv, wp_in, conv_b, in_proj_b, y16, xpad16);
    gF_dwln_offmask<<<NPIX / 64, 256, 0, stream>>>(y16, wp_om, dwT, dw_b, ln_g, ln_b, off_b, mask_b, tapmeta);
    kD_gather<<<NPIX / 8, 256, 0, stream>>>(xpad16, tapmeta, core16);
    g4_outproj<<<NPIX / 64, 256, 0, stream>>>(core16, wp_out, out_proj_b, out);
}

// Round 7
// 173.785 us; speedup vs baseline: 1.6569x; 1.0932x over previous
//
#include <hip/hip_runtime.h>
#include <math.h>

#define BB 8
#define CH 128
#define HH 64
#define WWID 64
#define HIN 62
#define WIN 62
#define SPIN (HIN*WIN)      // 3844
#define HP 66
#define WP 66
#define GG 4
#define GCH 32
#define NPIX (BB*HH*WWID)   // 32768
#define ASTRIDE 136         // LDS A-tile row stride in halfs

typedef _Float16 v8h __attribute__((ext_vector_type(8)));
typedef _Float16 v4h __attribute__((ext_vector_type(4)));
typedef float    v4f __attribute__((ext_vector_type(4)));

// ---- P0: pack 4 weight mats into MFMA B-frag order (f16) + dwT transpose ---
__global__ __launch_bounds__(256) void p0_pack(const float* __restrict__ conv_w,
                                               const float* __restrict__ in_proj_w,
                                               const float* __restrict__ off_w,
                                               const float* __restrict__ mask_w,
                                               const float* __restrict__ out_proj_w,
                                               const float* __restrict__ dw_w,
                                               _Float16* __restrict__ wp,
                                               float* __restrict__ dwT) {
    int t = threadIdx.x;
    if (blockIdx.x == 31) {                         // dwT[tap][c] transpose
        if (t < 128) {
            #pragma unroll
            for (int tap = 0; tap < 9; tap++) dwT[tap * 128 + t] = dw_w[t * 9 + tap];
        }
        return;
    }
    int tid = blockIdx.x * 256 + t;                 // 0..7935
    int mat, base;
    if (tid < 2048)      { mat = 0; base = 0; }
    else if (tid < 4096) { mat = 1; base = 2048; }
    else if (tid < 5888) { mat = 2; base = 4096; }
    else                 { mat = 3; base = 5888; }
    int fi = tid - base;
    int nt = fi >> 8, rem = fi & 255, kc = rem >> 6, lane = rem & 63;
    int n = nt * 16 + (lane & 15);
    int kbase = kc * 32 + ((lane >> 4) & 3) * 8;
    _Float16* dst = wp + (size_t)tid * 8;
    #pragma unroll
    for (int j = 0; j < 8; j++) {
        int k = kbase + j;
        float v;
        if (mat == 0)      v = conv_w[n * CH + k];
        else if (mat == 1) v = in_proj_w[k * CH + n];
        else if (mat == 2) v = (n < 72) ? off_w[k * 72 + n]
                               : (n < 108 ? mask_w[k * 36 + (n - 72)] : 0.f);
        else               v = out_proj_w[k * CH + n];
        dst[j] = (_Float16)v;
    }
}

// ---- MFMA core, 8-wave split: wave wv -> m-tile wv>>1, nt base (wv&1)*4 ----
__device__ inline void mfma_loop8(const _Float16* __restrict__ a16,
                                  const _Float16* __restrict__ wp,
                                  v4f acc[4], int t) {
    int lane = t & 63;
    int wv = t >> 6;                                // 0..7
    int mt = wv >> 1, ntb = (wv & 1) * 4;
    const _Float16* abase = a16 + (mt * 16 + (lane & 15)) * ASTRIDE + ((lane >> 4) * 8);
    #pragma unroll
    for (int kc = 0; kc < 4; kc++) {
        v8h av = *(const v8h*)(abase + kc * 32);
        #pragma unroll
        for (int j = 0; j < 4; j++) {
            v8h bv = *(const v8h*)(wp + ((size_t)((ntb + j) * 4 + kc) * 64 + lane) * 8);
            acc[j] = __builtin_amdgcn_mfma_f32_16x16x32_f16(av, bv, acc[j], 0, 0, 0);
        }
    }
}

// write fp32 C-layout accs into a16 as f16 [px][c] (this wave's nt-half)
__device__ inline void acc_to_a16_8(_Float16* a16, v4f acc[4], int t) {
    int lane = t & 63, ncol = lane & 15;
    int wv = t >> 6;
    int m0 = (wv >> 1) * 16 + ((lane >> 4) * 4);
    int ntb = (wv & 1) * 4;
    #pragma unroll
    for (int j = 0; j < 4; j++)
        #pragma unroll
        for (int r = 0; r < 4; r++)
            a16[(m0 + r) * ASTRIDE + (ntb + j) * 16 + ncol] = (_Float16)acc[j][r];
}

// ---- gA: fused conv1x1(pad=1) + in_proj, all-MFMA; emits y16 + xpad16 ------
__global__ __launch_bounds__(512) void gA_conv_inproj(const float* __restrict__ x,
                                                      const _Float16* __restrict__ wp_conv,
                                                      const _Float16* __restrict__ wp_in,
                                                      const float* __restrict__ conv_b,
                                                      const float* __restrict__ in_b,
                                                      _Float16* __restrict__ y16,
                                                      _Float16* __restrict__ xpad16) {
    __shared__ _Float16 a16[64 * ASTRIDE];
    int pix0 = blockIdx.x * 64;                     // one row
    int t = threadIdx.x;
    int h = (pix0 >> 6) & 63, b = pix0 >> 12;
    bool hin = (h >= 1 && h <= 62);
    for (int q = t; q < 8192; q += 512) {
        int c = q >> 6, w = q & 63;
        float v = 0.f;
        if (hin && w >= 1 && w <= 62)
            v = x[((size_t)(b * CH + c)) * SPIN + (h - 1) * WIN + (w - 1)];
        a16[w * ASTRIDE + c] = (_Float16)v;
    }
    __syncthreads();
    int lane = t & 63, ncol = lane & 15;
    int ntb = ((t >> 6) & 1) * 4;
    v4f acc[4];
    #pragma unroll
    for (int j = 0; j < 4; j++) {
        float bv = conv_b[(ntb + j) * 16 + ncol];
        acc[j] = (v4f){bv, bv, bv, bv};
    }
    mfma_loop8(a16, wp_conv, acc, t);
    __syncthreads();                                // x-tile reads done
    acc_to_a16_8(a16, acc, t);                      // a16 = y tile (f16)
    __syncthreads();
    {
        _Float16* dst = y16 + (size_t)pix0 * CH;
        for (int q = t; q < 1024; q += 512)
            *(v8h*)&dst[q * 8] = *(const v8h*)&a16[(q >> 4) * ASTRIDE + (q & 15) * 8];
    }
    v4f acc2[4];
    #pragma unroll
    for (int j = 0; j < 4; j++) {
        float bv = in_b[(ntb + j) * 16 + ncol];
        acc2[j] = (v4f){bv, bv, bv, bv};
    }
    mfma_loop8(a16, wp_in, acc2, t);
    __syncthreads();                                // y-tile reads done
    acc_to_a16_8(a16, acc2, t);                     // a16 = x_proj tile (f16)
    __syncthreads();
    {
        _Float16* dst = xpad16 + (size_t)(((b * HP) + h + 1) * WP + 1) * CH;
        for (int q = t; q < 1024; q += 512)
            *(v8h*)&dst[q * 8] = *(const v8h*)&a16[(q >> 4) * ASTRIDE + (q & 15) * 8];
    }
}

// ---- gF: fused dw3x3 + LN + GELU + off/mask MFMA + softmax + taps ----------
// phase1 LDS: ylds = 3 rows x 16 c8 x 65(w-stride) v8h  = 49,920 B
// phase2 LDS: a16 (17,408 B) + om 64x112 f32 (28,672 B) = 46,080 B
__global__ __launch_bounds__(512) void gF_dwln_offmask(const _Float16* __restrict__ y16,
                                                       const _Float16* __restrict__ wp_om,
                                                       const float* __restrict__ dwT,
                                                       const float* __restrict__ dw_b,
                                                       const float* __restrict__ ln_g,
                                                       const float* __restrict__ ln_b,
                                                       const float* __restrict__ off_b,
                                                       const float* __restrict__ mask_b,
                                                       float* __restrict__ tapmeta) {
    __shared__ char smem[49920];
    _Float16* ylds = (_Float16*)smem;               // v8h idx: (r*16+c8)*65 + w
    int t = threadIdx.x;
    int pix0 = blockIdx.x * 64;
    int h = (pix0 >> 6) & 63, b = pix0 >> 12;
    if (h == 0 || h == 63) {                        // zero-fill for missing rows
        for (int i = t; i < 3120; i += 512) *(v8h*)&ylds[i * 8] = (v8h)(_Float16)0;
        __syncthreads();
    }
    for (int idx = t; idx < 3072; idx += 512) {
        int r = idx >> 10, w = (idx >> 4) & 63, c8 = idx & 15;
        int hh = h + r - 1;
        if (hh >= 0 && hh <= 63) {
            v8h v = *(const v8h*)&y16[(size_t)(((b * 64 + hh) * 64 + w) * CH) + c8 * 8];
            *(v8h*)&ylds[(size_t)((r * 16 + c8) * 65 + w) * 8] = v;
        }
    }
    __syncthreads();
    // ---- depthwise conv, 1 px x 16 ch per thread (px = t>>3, q8 = t&7) ----
    int px = t >> 3, q8 = t & 7;
    float acc[16];
    #pragma unroll
    for (int cb = 0; cb < 4; cb++) *(float4*)&acc[cb * 4] = *(const float4*)&dw_b[q8 * 16 + cb * 4];
    #pragma unroll
    for (int r = 0; r < 3; r++) {
        #pragma unroll
        for (int kx = 0; kx < 3; kx++) {
            int wq = px + kx - 1;
            bool valid = (wq >= 0 && wq <= 63);
            int wpc = min(max(wq, 0), 63);
            int tap = r * 3 + kx;
            if (valid) {
                #pragma unroll
                for (int cb = 0; cb < 2; cb++) {
                    v8h yv = *(const v8h*)&ylds[(size_t)((r * 16 + q8 * 2 + cb) * 65 + wpc) * 8];
                    float4 wa = *(const float4*)&dwT[tap * 128 + q8 * 16 + cb * 8];
                    float4 wb = *(const float4*)&dwT[tap * 128 + q8 * 16 + cb * 8 + 4];
                    acc[cb*8+0] += (float)yv[0] * wa.x; acc[cb*8+1] += (float)yv[1] * wa.y;
                    acc[cb*8+2] += (float)yv[2] * wa.z; acc[cb*8+3] += (float)yv[3] * wa.w;
                    acc[cb*8+4] += (float)yv[4] * wb.x; acc[cb*8+5] += (float)yv[5] * wb.y;
                    acc[cb*8+6] += (float)yv[6] * wb.z; acc[cb*8+7] += (float)yv[7] * wb.w;
                }
            }
        }
    }
    // ---- LayerNorm over 128 ch = 8 threads x 16 ----
    float s = 0.f, ss = 0.f;
    #pragma unroll
    for (int j = 0; j < 16; j++) { s += acc[j]; ss += acc[j] * acc[j]; }
    s  += __shfl_xor(s, 1);  s  += __shfl_xor(s, 2);  s  += __shfl_xor(s, 4);
    ss += __shfl_xor(ss, 1); ss += __shfl_xor(ss, 2); ss += __shfl_xor(ss, 4);
    float mu = s * (1.f / 128.f);
    float var = ss * (1.f / 128.f) - mu * mu;
    float rstd = rsqrtf(var + 1e-5f);
    v8h dreg[2];
    #pragma unroll
    for (int cb = 0; cb < 2; cb++) {
        float4 ga = *(const float4*)&ln_g[q8 * 16 + cb * 8];
        float4 gb = *(const float4*)&ln_g[q8 * 16 + cb * 8 + 4];
        float4 ba = *(const float4*)&ln_b[q8 * 16 + cb * 8];
        float4 bb = *(const float4*)&ln_b[q8 * 16 + cb * 8 + 4];
        float gv[8] = {ga.x, ga.y, ga.z, ga.w, gb.x, gb.y, gb.z, gb.w};
        float bv[8] = {ba.x, ba.y, ba.z, ba.w, bb.x, bb.y, bb.z, bb.w};
        #pragma unroll
        for (int j = 0; j < 8; j++) {
            float xln = (acc[cb * 8 + j] - mu) * rstd * gv[j] + bv[j];
            float gel = 0.5f * xln * (1.f + erff(xln * 0.70710678118654752f));
            dreg[cb][j] = (_Float16)gel;
        }
    }
    __syncthreads();                                // ylds dead
    _Float16* a16 = (_Float16*)smem;
    float* om = (float*)(smem + 17408);
    #pragma unroll
    for (int cb = 0; cb < 2; cb++)
        *(v8h*)&a16[px * ASTRIDE + q8 * 16 + cb * 8] = dreg[cb];
    __syncthreads();
    // ---- off/mask GEMM via MFMA (NT=7; phantom nt=7 computed, not stored) --
    int lane = t & 63, ncol = lane & 15;
    int ntb = ((t >> 6) & 1) * 4;
    v4f macc[4];
    #pragma unroll
    for (int j = 0; j < 4; j++) {
        int n = (ntb + j) * 16 + ncol;
        float bv = (n < 72) ? off_b[n] : (n < 108 ? mask_b[n - 72] : 0.f);
        macc[j] = (v4f){bv, bv, bv, bv};
    }
    mfma_loop8(a16, wp_om, macc, t);
    int m0 = ((t >> 6) >> 1) * 16 + ((lane >> 4) * 4);
    #pragma unroll
    for (int j = 0; j < 4; j++) {
        if (ntb + j < 7) {
            #pragma unroll
            for (int r = 0; r < 4; r++)
                om[(m0 + r) * 112 + (ntb + j) * 16 + ncol] = macc[j][r];
        }
    }
    __syncthreads();
    // ---- softmax + tap precompute: threads 0..255 -> (px, g) ----
    if (t < 256) {
        int pxs = t >> 2, gx = t & 3;
        const float* row = &om[pxs * 112];
        float lg[9];
        #pragma unroll
        for (int i = 0; i < 9; i++) lg[i] = row[72 + gx * 9 + i];
        float mx = lg[0];
        #pragma unroll
        for (int i = 1; i < 9; i++) mx = fmaxf(mx, lg[i]);
        float e[9], sum = 0.f;
        #pragma unroll
        for (int i = 0; i < 9; i++) { e[i] = expf(lg[i] - mx); sum += e[i]; }
        float inv = 1.f / sum;
        float* tm = tapmeta + ((size_t)(pix0 + pxs) * 36 + gx * 9) * 8;
        #pragma unroll
        for (int p = 0; p < 9; p++) {
            int gp = gx * 9 + p;
            float offx = row[gp * 2];
            float offy = row[gp * 2 + 1];
            float m = e[p] * inv;
            float ix = (float)(pxs + (p / 3)) + offx;
            float iy = (float)(h + (p % 3)) + offy;
            float x0f = floorf(ix), y0f = floorf(iy);
            float fx = ix - x0f, fy = iy - y0f;
            int x0 = (int)x0f, y0 = (int)y0f;
            int xi[4] = { x0, x0 + 1, x0,     x0 + 1 };
            int yi[4] = { y0, y0,     y0 + 1, y0 + 1 };
            float wt[4] = { m * (1.f - fx) * (1.f - fy), m * fx * (1.f - fy),
                            m * (1.f - fx) * fy,         m * fx * fy };
            int lo[4];
            #pragma unroll
            for (int cnr = 0; cnr < 4; cnr++) {
                bool vv = ((unsigned)xi[cnr] < (unsigned)WP) && ((unsigned)yi[cnr] < (unsigned)HP);
                int xc = min(max(xi[cnr], 0), WP - 1), yc = min(max(yi[cnr], 0), HP - 1);
                lo[cnr] = (yc * WP + xc) * CH;
                if (!vv) wt[cnr] = 0.f;
            }
            *(int4*)&tm[p * 8]       = make_int4(lo[0], lo[1], lo[2], lo[3]);
            *(float4*)&tm[p * 8 + 4] = make_float4(wt[0], wt[1], wt[2], wt[3]);
        }
    }
}

// ---- kD: gather sampling, 8 px/block, 4 ch/thread -> core16 ----------------
__global__ __launch_bounds__(256) void kD_gather(const _Float16* __restrict__ xpad16,
                                                 const float* __restrict__ tapmeta,
                                                 _Float16* __restrict__ core16) {
    __shared__ float meta[8 * 36 * 8];              // 9216 B
    int t = threadIdx.x;
    int pix0 = blockIdx.x * 8;
    const float4* src = (const float4*)(tapmeta + (size_t)pix0 * 36 * 8);
    for (int i = t; i < 576; i += 256) ((float4*)meta)[i] = src[i];
    __syncthreads();
    int px_l = t >> 5, lane5 = t & 31;
    int c4 = lane5 * 4, g = lane5 >> 3;
    int pix = pix0 + px_l;
    int b = pix >> 12;
    const _Float16* base = xpad16 + (size_t)b * HP * WP * CH + c4;
    float a0 = 0.f, a1 = 0.f, a2 = 0.f, a3 = 0.f;
    #pragma unroll
    for (int p = 0; p < 9; p++) {
        const float* rec = &meta[(size_t)(px_l * 36 + g * 9 + p) * 8];
        int4   o  = *(const int4*)rec;
        float4 wv = *(const float4*)(rec + 4);
        v4h h0 = *(const v4h*)&base[o.x];
        v4h h1 = *(const v4h*)&base[o.y];
        v4h h2 = *(const v4h*)&base[o.z];
        v4h h3 = *(const v4h*)&base[o.w];
        a0 += wv.x*(float)h0[0] + wv.y*(float)h1[0] + wv.z*(float)h2[0] + wv.w*(float)h3[0];
        a1 += wv.x*(float)h0[1] + wv.y*(float)h1[1] + wv.z*(float)h2[1] + wv.w*(float)h3[1];
        a2 += wv.x*(float)h0[2] + wv.y*(float)h1[2] + wv.z*(float)h2[2] + wv.w*(float)h3[2];
        a3 += wv.x*(float)h0[3] + wv.y*(float)h1[3] + wv.z*(float)h2[3] + wv.w*(float)h3[3];
    }
    v4h res = { (_Float16)a0, (_Float16)a1, (_Float16)a2, (_Float16)a3 };
    *(v4h*)&core16[(size_t)pix * CH + c4] = res;
}

// ---- g4: out_proj via MFMA + NHWC->NCHW store ------------------------------
__global__ __launch_bounds__(512) void g4_outproj(const _Float16* __restrict__ core16,
                                                  const _Float16* __restrict__ wp,
                                                  const float* __restrict__ bias,
                                                  float* __restrict__ out) {
    __shared__ _Float16 a16[64 * ASTRIDE];
    __shared__ float res[64 * 129];
    int pix0 = blockIdx.x * 64;
    int t = threadIdx.x;
    const _Float16* src = core16 + (size_t)pix0 * CH;
    for (int q = t; q < 1024; q += 512)
        *(v8h*)&a16[(q >> 4) * ASTRIDE + (q & 15) * 8] = *(const v8h*)&src[q * 8];
    __syncthreads();
    int lane = t & 63, ncol = lane & 15;
    int ntb = ((t >> 6) & 1) * 4;
    v4f acc[4];
    #pragma unroll
    for (int j = 0; j < 4; j++) {
        float bv = bias[(ntb + j) * 16 + ncol];
        acc[j] = (v4f){bv, bv, bv, bv};
    }
    mfma_loop8(a16, wp, acc, t);
    int m0 = ((t >> 6) >> 1) * 16 + ((lane >> 4) * 4);
    #pragma unroll
    for (int j = 0; j < 4; j++)
        #pragma unroll
        for (int r = 0; r < 4; r++)
            res[(m0 + r) * 129 + (ntb + j) * 16 + ncol] = acc[j][r];
    __syncthreads();
    int b = pix0 >> 12, h = (pix0 >> 6) & 63;
    for (int q = t; q < 8192; q += 512) {
        int cc = q >> 6, ww = q & 63;
        out[(size_t)((b * CH + cc) * HH + h) * WWID + ww] = res[ww * 129 + cc];
    }
}

extern "C" void kernel_launch(void* const* d_in, const int* in_sizes, int n_in,
                              void* d_out, int out_size, void* d_ws, size_t ws_size,
                              hipStream_t stream) {
    const float* x        = (const float*)d_in[0];
    const float* conv_w   = (const float*)d_in[1];
    const float* conv_b   = (const float*)d_in[2];
    const float* in_proj_w= (const float*)d_in[3];
    const float* in_proj_b= (const float*)d_in[4];
    const float* dw_w     = (const float*)d_in[5];
    const float* dw_b     = (const float*)d_in[6];
    const float* ln_g     = (const float*)d_in[7];
    const float* ln_b     = (const float*)d_in[8];
    const float* off_w    = (const float*)d_in[9];
    const float* off_b    = (const float*)d_in[10];
    const float* mask_w   = (const float*)d_in[11];
    const float* mask_b   = (const float*)d_in[12];
    const float* out_proj_w = (const float*)d_in[13];
    const float* out_proj_b = (const float*)d_in[14];
    float* out = (float*)d_out;

    float* ws = (float*)d_ws;
    // float-offsets: wp(32768) | dwT(2048) | y16 | xpad16 | core16 | tapmeta
    const size_t O_WP   = 0;                       // 7936*8 halfs = 124 KB
    const size_t O_DWT  = 32768;                   // 1152 floats
    const size_t O_Y16  = 34816;                   // 2,097,152 floats (as halfs)
    const size_t O_XP16 = O_Y16 + 2097152;         // 2,230,272 floats
    const size_t O_C16  = O_XP16 + 2230272;        // 2,097,152 floats
    const size_t O_TM   = O_C16 + 2097152;         // 9,437,184 floats
    _Float16* wp     = (_Float16*)(ws + O_WP);
    float*    dwT    = ws + O_DWT;
    _Float16* y16    = (_Float16*)(ws + O_Y16);
    _Float16* xpad16 = (_Float16*)(ws + O_XP16);
    _Float16* core16 = (_Float16*)(ws + O_C16);
    float*    tapmeta= ws + O_TM;

    _Float16* wp_conv = wp;
    _Float16* wp_in   = wp + (size_t)2048 * 8;
    _Float16* wp_om   = wp + (size_t)4096 * 8;
    _Float16* wp_out  = wp + (size_t)5888 * 8;

    p0_pack<<<32, 256, 0, stream>>>(conv_w, in_proj_w, off_w, mask_w, out_proj_w, dw_w, wp, dwT);
    hipMemsetAsync(xpad16, 0, (size_t)8 * HP * WP * CH * sizeof(_Float16), stream);
    gA_conv_inproj<<<NPIX / 64, 512, 0, stream>>>(x, wp_conv, wp_in, conv_b, in_proj_b, y16, xpad16);
    gF_dwln_offmask<<<NPIX / 64, 512, 0, stream>>>(y16, wp_om, dwT, dw_b, ln_g, ln_b, off_b, mask_b, tapmeta);
    kD_gather<<<NPIX / 8, 256, 0, stream>>>(xpad16, tapmeta, core16);
    g4_outproj<<<NPIX / 64, 512, 0, stream>>>(core16, wp_out, out_proj_b, out);
}